// Round 13
// baseline (146.932 us; speedup 1.0000x reference)
//
#include <hip/hip_runtime.h>
#include <math.h>

#define BATCH 64
#define H 512
#define W 512
#define SROWS 128              // output rows per wave
#define NSTRIP (H / SROWS)     // 4 strips
#define WPB 4                  // waves per block (adjacent col-groups share halo in L1)
// 16 col-groups of 32 cols; grid = 64 img * 4 strips * 4 clusters = 1024 blocks

__device__ __forceinline__ float wave_reduce(float v) {
    #pragma unroll
    for (int off = 32; off > 0; off >>= 1) v += __shfl_xor(v, off);
    return v;
}

// Barrier-free fused kernel. Per wave: 32 output cols, 128 rows.
//  - lane l holds column cl = c0-15+l (62 lanes active: out cols + /-15 halo)
//  - vertical 31-window via running prefix Vrun and a 32-deep register ring
//    (all indices compile-time static): vraw(y) = P(y+15) - P(y-16)
//  - horizontal 31-window via wave prefix-scan + 2 shuffles:
//    out[j] = HP[j+30] - HP[j-1]  (lanes j=0..31)
//  - rows processed in pairs; loss math occupies all 64 lanes (2 rows x 32 cols)
__global__ __launch_bounds__(256) void fused_kernel(const float* __restrict__ pred,
                                                    const float* __restrict__ mask,
                                                    float2* __restrict__ partials) {
    const int tid  = threadIdx.x;
    const int wv   = tid >> 6;
    const int lane = tid & 63;
    const int bid  = blockIdx.x;
    const int img  = bid >> 4;               // 16 blocks per image
    const int rem  = bid & 15;
    const int strip= rem >> 2;               // 4 strips
    const int cgc  = rem & 3;                // cluster of 4 col-groups
    const int c0   = (cgc * WPB + wv) * 32;  // first output column
    const int y0   = strip * SROWS;          // y0 % 32 == 0 (static ring slots)
    const size_t base = (size_t)img * (H * W);
    const float* mk = mask + base;
    const float* pr = pred + base;

    const int  cl = c0 - 15 + lane;                          // vraw column
    const bool vvalid = (lane < 62) && (cl >= 0) && (cl < W);
    const int  j      = lane & 31;
    const int  rowoff = lane >> 5;                           // 0 or 1 (row of pair)
    const int  cm     = c0 + j;                              // loss column

    // ---- vertical prefix ring (32 registers, static indexing) ----
    // ring[r & 31] = P(r) = sum of mask rows (y0-15 .. r) for this lane's column.
    float ring[32];
    float Vrun = 0.f;
    ring[16] = 0.f;                                          // P(y0-16) = 0
    #pragma unroll
    for (int u = 0; u < 30; ++u) {                           // rows y0-15 .. y0+14
        const int r = y0 - 15 + u;
        float v = 0.f;
        if (vvalid && r >= 0) v = mk[(size_t)r * W + cl];
        Vrun += v;
        ring[(u + 17) & 31] = Vrun;                          // slot r & 31
    }

    float s0 = 0.f, s1 = 0.f;
    const float inv_k2 = 1.0f / 961.0f;

    for (int b = 0; b < SROWS / 32; ++b) {                   // 4 (rolled; slots repeat)
        const int yb = y0 + 32 * b;
        #pragma unroll
        for (int tp = 0; tp < 16; ++tp) {                    // pairs of rows
            float win0, win1;
            #pragma unroll
            for (int h = 0; h < 2; ++h) {
                const int t = 2 * tp + h;                    // 0..31 static
                const int radd = yb + t + 15;                // row to add
                float v = 0.f;
                if (vvalid && radd < H) v = mk[(size_t)radd * W + cl];
                Vrun += v;                                   // = P(y+15) (clamped top)
                const float Pold = ring[(t + 16) & 31];      // P(y-16)
                ring[(t + 15) & 31] = Vrun;
                float hp = Vrun - Pold;                      // vraw at (y, cl)
                // wave inclusive prefix over lanes
                #pragma unroll
                for (int off = 1; off < 64; off <<= 1) {
                    const float n = __shfl_up(hp, off);
                    if (lane >= off) hp += n;
                }
                const float a = __shfl_down(hp, 30);         // HP[l+30]
                float bb = __shfl_up(hp, 1);                 // HP[l-1]
                if (lane == 0) bb = 0.f;
                const float w = a - bb;                      // box sum, lanes 0..31
                if (h == 0) win0 = w; else win1 = w;
            }
            // redistribute: lanes 0..31 take win0[j] (in place), 32..63 take win1[j]
            const float w1s = __shfl_up(win1, 32);
            const float myw = (lane < 32) ? win0 : w1s;

            const int ym = yb + 2 * tp + rowoff;
            const float m = mk[(size_t)ym * W + cm];
            const float p = pr[(size_t)ym * W + cm];

            const float avg = myw * inv_k2;
            const float wgt = 1.0f + 5.0f * fabsf(avg - m);
            const float e = __expf(-fabsf(p));
            const float softplus = __logf(1.0f + e);         // log1p(e), e in (0,1]
            const float bce = fmaxf(p, 0.0f) - p * m + softplus;
            const float r1pe = __builtin_amdgcn_rcpf(1.0f + e);
            const float sig = (p >= 0.0f) ? r1pe : e * r1pe;
            const float inter = sig * m;
            const float denom = sig + m - inter + 1.0f;      // union - inter + 1
            const float iou = 1.0f - (inter + 1.0f) * __builtin_amdgcn_rcpf(denom);
            s0 += wgt;
            s1 += wgt * (bce + iou);
        }
    }

    s0 = wave_reduce(s0);
    s1 = wave_reduce(s1);
    if (lane == 0) partials[bid * WPB + wv] = make_float2(s0, s1);
}

// -------- Finalize: per-image ratio (64 wave-partials each), mean over images.
__global__ void finalize_kernel(const float2* __restrict__ partials,
                                float* __restrict__ out) {
    const int lane = threadIdx.x;   // 64 threads, one per image
    float s0 = 0.f, s1 = 0.f;
    for (int k = 0; k < 64; ++k) {
        const float2 pp = partials[lane * 64 + k];
        s0 += pp.x; s1 += pp.y;
    }
    float q = s1 / s0;
    q = wave_reduce(q);
    if (lane == 0) out[0] = q * (1.0f / (float)BATCH);
}

extern "C" void kernel_launch(void* const* d_in, const int* in_sizes, int n_in,
                              void* d_out, int out_size, void* d_ws, size_t ws_size,
                              hipStream_t stream) {
    const float* pred = (const float*)d_in[0];
    const float* mask = (const float*)d_in[1];
    float2* partials = (float2*)d_ws;   // 4096 * 8B

    hipLaunchKernelGGL(fused_kernel, dim3(BATCH * NSTRIP * 4), dim3(256), 0, stream,
                       pred, mask, partials);
    hipLaunchKernelGGL(finalize_kernel, dim3(1), dim3(64), 0, stream,
                       partials, (float*)d_out);
}

// Round 14
// 41.937 us; speedup vs baseline: 3.5037x; 3.5037x over previous
//
#include <hip/hip_runtime.h>
#include <math.h>

#define BATCH 64
#define H 512
#define W 512
#define KRAD 15
#define STRIP 64               // output rows per block
#define NSTRIP (H / STRIP)     // 8 strips per image
#define RING 48                // LDS ring slots; live span/group = 39, +8 write-ahead = 47 <= 48

__device__ __forceinline__ float wave_reduce(float v) {
    #pragma unroll
    for (int off = 32; off > 0; off >>= 1) v += __shfl_xor(v, off);
    return v;
}

// f32 -> bf16 bits (round-to-nearest-even)
__device__ __forceinline__ unsigned bf16b(float f) {
    unsigned u = __float_as_uint(f);
    return (u + 0x7FFFu + ((u >> 16) & 1u)) >> 16;
}
__device__ __forceinline__ float fbf16(unsigned short s) {
    return __uint_as_float(((unsigned)s) << 16);
}

// One wave: 31-wide horizontal box sum of mask row r (zero padded), bf16-pack
// into ring row dst. Chain-free: lane L owns x in [8L, 8L+8);
//   out[k] = suffix_{L-2}(k+1) + T_{L-1} + T_L + T_{L+1} + prefix_{L+2}(k-1)
// All 17 shuffles independent (no serial wave-scan); edge-lane masking = zero pad.
__device__ __forceinline__ void scan_row(const float* __restrict__ img_base, int r,
                                         int lane, unsigned short* dst) {
    float o[8];
    if (0 <= r && r < H) {
        const float4* in4 = reinterpret_cast<const float4*>(img_base + (size_t)r * W + lane * 8);
        float4 va = in4[0], vb = in4[1];
        float v[8] = {va.x, va.y, va.z, va.w, vb.x, vb.y, vb.z, vb.w};
        float P[8];
        P[0] = v[0];
        #pragma unroll
        for (int k = 1; k < 8; ++k) P[k] = P[k - 1] + v[k];
        const float T = P[7];

        float Tm1 = __shfl_up(T, 1);
        float Tm2 = __shfl_up(T, 2);
        float Tp1 = __shfl_down(T, 1);
        float Pm2[7], Pp2[7];
        #pragma unroll
        for (int k = 0; k < 7; ++k) Pm2[k] = __shfl_up(P[k], 2);
        #pragma unroll
        for (int k = 0; k < 7; ++k) Pp2[k] = __shfl_down(P[k], 2);

        if (lane < 1) Tm1 = 0.f;
        if (lane < 2) {
            Tm2 = 0.f;
            #pragma unroll
            for (int k = 0; k < 7; ++k) Pm2[k] = 0.f;
        }
        if (lane > 62) Tp1 = 0.f;
        if (lane > 61) {
            #pragma unroll
            for (int k = 0; k < 7; ++k) Pp2[k] = 0.f;
        }

        const float C = Tm1 + T + Tp1;
        o[0] = C + (Tm2 - Pm2[0]);
        #pragma unroll
        for (int k = 1; k < 7; ++k) o[k] = C + (Tm2 - Pm2[k]) + Pp2[k - 1];
        o[7] = C + Pp2[6];
    } else {
        #pragma unroll
        for (int k = 0; k < 8; ++k) o[k] = 0.f;
    }
    uint4 wv;
    wv.x = bf16b(o[0]) | (bf16b(o[1]) << 16);
    wv.y = bf16b(o[2]) | (bf16b(o[3]) << 16);
    wv.z = bf16b(o[4]) | (bf16b(o[5]) << 16);
    wv.w = bf16b(o[6]) | (bf16b(o[7]) << 16);
    *reinterpret_cast<uint4*>(dst + lane * 8) = wv;      // 16B, conflict-free
}

// -------- Fused: chain-free scan -> 48-slot bf16 LDS ring -> vertical window + loss.
// ONE barrier per 8-row group (write-ahead slots provably disjoint; see R11).
__global__ __launch_bounds__(512) void fused_kernel(const float* __restrict__ pred,
                                                    const float* __restrict__ mask,
                                                    float2* __restrict__ partials) {
    __shared__ unsigned short ring[RING][W];             // 49152 B

    const int tid  = threadIdx.x;
    const int wave = tid >> 6;
    const int lane = tid & 63;
    const int img   = blockIdx.x >> 3;                   // NSTRIP = 8
    const int strip = blockIdx.x & 7;
    const int r0 = strip * STRIP;
    const int c  = tid;
    const float* mk = mask + (size_t)img * (H * W);
    const float* pr = pred + (size_t)img * (H * W);

    // Prologue: fill slots 0..30 (rows r0-16 .. r0+14)
    #pragma unroll
    for (int gp = 0; gp < 4; ++gp) {
        const int idx = gp * 8 + wave;
        if (idx < 31) scan_row(mk, r0 - 16 + idx, lane, &ring[idx][0]);
    }
    __syncthreads();

    // Initial vertical sum: slots 1..30 (rows r0-15 .. r0+14)
    float vsum = 0.f;
    #pragma unroll
    for (int s = 1; s <= 30; ++s) vsum += fbf16(ring[s][c]);

    float s0 = 0.f, s1 = 0.f;
    const float inv_k2 = 1.0f / 961.0f;
    int sA = 31;   // (8g+31) % 48
    int sB = 0;    //  8g     % 48

    for (int g = 0; g < STRIP / 8; ++g) {
        const int ybase = r0 + 8 * g;
        // Phase A: scan row ybase+15+wave into slot (sA+wave) mod 48
        {
            int slot = sA + wave;
            if (slot >= RING) slot -= RING;
            scan_row(mk, ybase + 15 + wave, lane, &ring[slot][0]);
        }
        __syncthreads();   // the ONLY barrier per group

        // Phase B: issue global m/p loads first (latency hides under LDS+math)
        float m[8], p[8];
        #pragma unroll
        for (int i = 0; i < 8; ++i) {
            const int y = ybase + i;
            m[i] = mk[(size_t)y * W + c];
            p[i] = pr[(size_t)y * W + c];
        }
        float addv[8], subv[8];
        #pragma unroll
        for (int i = 0; i < 8; ++i) {
            int slotA = sA + i;
            if (slotA >= RING) slotA -= RING;
            addv[i] = fbf16(ring[slotA][c]);
            subv[i] = fbf16(ring[sB + i][c]);            // sB+i <= 47, never wraps
        }
        // window sums first (short serial chain), then 8 independent math bodies
        float ws[8];
        {
            float acc = vsum;
            #pragma unroll
            for (int i = 0; i < 8; ++i) { acc += addv[i] - subv[i]; ws[i] = acc; }
            vsum = acc;
        }
        #pragma unroll
        for (int i = 0; i < 8; ++i) {
            const float avg = ws[i] * inv_k2;
            const float w = 1.0f + 5.0f * fabsf(avg - m[i]);

            const float e = __expf(-fabsf(p[i]));        // 1 trans
            const float u = 1.0f + e;
            const float softplus = __logf(u);            // log1p(e); 1 trans
            const float bce = fmaxf(p[i], 0.0f) - p[i] * m[i] + softplus;

            // sigmoid-free IoU: with a = (p>=0 ? 1 : e), sig = a/u,
            //   (inter+1)/denom = (a*m + u) / (a*(1-m) + (m+1)*u)   -- single rcp
            const float a = (p[i] >= 0.0f) ? 1.0f : e;
            const float num = a * m[i] + u;
            const float den = a * (1.0f - m[i]) + (m[i] + 1.0f) * u;
            const float iou = 1.0f - num * __builtin_amdgcn_rcpf(den);  // 1 trans

            s0 += w;
            s1 += w * (bce + iou);
        }
        sA += 8; if (sA >= RING) sA -= RING;
        sB += 8; if (sB >= RING) sB -= RING;
        // no tail barrier: RING=48 slack covers the one-group write-ahead
    }

    s0 = wave_reduce(s0);
    s1 = wave_reduce(s1);
    __syncthreads();                                     // all ring reads done
    float2* wacc = reinterpret_cast<float2*>(&ring[0][0]);   // alias: ring dead now
    if (lane == 0) wacc[wave] = make_float2(s0, s1);
    __syncthreads();
    if (tid == 0) {
        float a0 = 0.f, a1 = 0.f;
        #pragma unroll
        for (int i = 0; i < 8; ++i) { a0 += wacc[i].x; a1 += wacc[i].y; }
        partials[blockIdx.x] = make_float2(a0, a1);
    }
}

// -------- Finalize: per-image ratio, mean over 64 images. One wave.
__global__ void finalize_kernel(const float2* __restrict__ partials,
                                float* __restrict__ out) {
    const int lane = threadIdx.x;   // 64 threads, one per image
    float s0 = 0.f, s1 = 0.f;
    #pragma unroll
    for (int j = 0; j < NSTRIP; ++j) {
        const float2 pp = partials[lane * NSTRIP + j];
        s0 += pp.x; s1 += pp.y;
    }
    float q = s1 / s0;
    q = wave_reduce(q);
    if (lane == 0) out[0] = q * (1.0f / (float)BATCH);
}

extern "C" void kernel_launch(void* const* d_in, const int* in_sizes, int n_in,
                              void* d_out, int out_size, void* d_ws, size_t ws_size,
                              hipStream_t stream) {
    const float* pred = (const float*)d_in[0];
    const float* mask = (const float*)d_in[1];
    float2* partials = (float2*)d_ws;   // 512 * 8B

    hipLaunchKernelGGL(fused_kernel, dim3(BATCH * NSTRIP), dim3(512), 0, stream,
                       pred, mask, partials);
    hipLaunchKernelGGL(finalize_kernel, dim3(1), dim3(64), 0, stream,
                       partials, (float*)d_out);
}